// Round 1
// baseline (962.889 us; speedup 1.0000x reference)
//
#include <hip/hip_runtime.h>
#include <hip/hip_bf16.h>

#define ALPHA 0.2f
#define NEGV  -9000000000000000.0f

typedef __attribute__((ext_vector_type(8))) short bf16x8;
typedef __attribute__((ext_vector_type(4))) float f32x4;

// fp32 -> bf16 (RNE) bit trick; inputs are finite so no NaN care needed.
__device__ __forceinline__ short f2b(float f) {
  unsigned u = __float_as_uint(f);
  unsigned r = (u + 0x7FFFu + ((u >> 16) & 1u)) >> 16;
  return (short)r;
}

// ---------------- Kernel 1: Wh[h,b,n,o] = sum_i x[b,n,i] * W[h,b,i,o] ----------------
// grid 512 = (h*32+b)*4 + kchunk ; 256 threads; k-split 4 with atomicAdd into zeroed Wh.
__global__ __launch_bounds__(256) void k1_wh(const float* __restrict__ x,
                                             const float* __restrict__ W,
                                             float* __restrict__ Wh) {
  int blk = blockIdx.x;
  int kc = blk & 3;
  int hb = blk >> 2;          // h*32+b
  int b  = hb & 31;
  int t  = threadIdx.x;
  __shared__ float xs[14][256];
  int i0 = kc * 256;
  const float* xb = x + (size_t)b * 14 * 1024 + i0;
  #pragma unroll
  for (int n = 0; n < 14; ++n) xs[n][t] = xb[n * 1024 + t];
  __syncthreads();

  const float* Wp = W + ((size_t)hb * 1024 + i0) * 1024 + 4 * t;   // o = 4t..4t+3
  float4 acc[14];
  #pragma unroll
  for (int n = 0; n < 14; ++n) acc[n] = make_float4(0.f, 0.f, 0.f, 0.f);

  for (int ii = 0; ii < 256; ii += 4) {
    float4 w0 = *(const float4*)(Wp + (size_t)(ii + 0) * 1024);
    float4 w1 = *(const float4*)(Wp + (size_t)(ii + 1) * 1024);
    float4 w2 = *(const float4*)(Wp + (size_t)(ii + 2) * 1024);
    float4 w3 = *(const float4*)(Wp + (size_t)(ii + 3) * 1024);
    #pragma unroll
    for (int n = 0; n < 14; ++n) {
      float4 xn = *(const float4*)&xs[n][ii];   // wave-uniform -> LDS broadcast
      acc[n].x += xn.x * w0.x + xn.y * w1.x + xn.z * w2.x + xn.w * w3.x;
      acc[n].y += xn.x * w0.y + xn.y * w1.y + xn.z * w2.y + xn.w * w3.y;
      acc[n].z += xn.x * w0.z + xn.y * w1.z + xn.z * w2.z + xn.w * w3.z;
      acc[n].w += xn.x * w0.w + xn.y * w1.w + xn.z * w2.w + xn.w * w3.w;
    }
  }

  float* dst = Wh + (size_t)hb * 14336 + 4 * t;
  #pragma unroll
  for (int n = 0; n < 14; ++n) {
    atomicAdd(dst + n * 1024 + 0, acc[n].x);
    atomicAdd(dst + n * 1024 + 1, acc[n].y);
    atomicAdd(dst + n * 1024 + 2, acc[n].z);
    atomicAdd(dst + n * 1024 + 3, acc[n].w);
  }
}

// ---------------- Kernel 2: attention matrix (softmax over axis=2 == n, per column m) ----------------
// grid 128 = h*32+b ; 64 threads (1 wave).
__global__ __launch_bounds__(64) void k2_att(const float* __restrict__ Wh,
                                             const float* __restrict__ adj,
                                             const float* __restrict__ a,
                                             float* __restrict__ att) {
  int hb = blockIdx.x;
  int b  = hb & 31;
  int l  = threadIdx.x;
  __shared__ float wh1s[14], wh2s[14];
  const float* whp = Wh + (size_t)hb * 14336;
  const float* a1  = a + (size_t)hb * 2048;
  const float* a2  = a1 + 1024;

  for (int n = 0; n < 14; ++n) {
    float p1 = 0.f, p2 = 0.f;
    #pragma unroll
    for (int j = 0; j < 16; ++j) {
      int o = l + 64 * j;
      float wv = whp[n * 1024 + o];
      p1 += wv * a1[o];
      p2 += wv * a2[o];
    }
    #pragma unroll
    for (int s = 32; s >= 1; s >>= 1) {
      p1 += __shfl_xor(p1, s);
      p2 += __shfl_xor(p2, s);
    }
    if (l == 0) { wh1s[n] = p1; wh2s[n] = p2; }
  }
  __syncthreads();

  if (l < 14) {
    int m = l;
    const float* adjb = adj + b * 196;
    float col[14];
    float mx = -1e30f;
    #pragma unroll
    for (int n = 0; n < 14; ++n) {
      float e = wh1s[n] + wh2s[m];
      e = (e > 0.f) ? e : ALPHA * e;
      e = (adjb[n * 14 + m] > 0.f) ? e : NEGV;
      col[n] = e;
      mx = fmaxf(mx, e);
    }
    float s = 0.f;
    #pragma unroll
    for (int n = 0; n < 14; ++n) { col[n] = expf(col[n] - mx); s += col[n]; }
    float inv = 1.f / s;
    #pragma unroll
    for (int n = 0; n < 14; ++n) att[hb * 196 + n * 14 + m] = col[n] * inv;
  }
}

// ---------------- Kernel 3: h_prime[h,b,n,o] = sum_m att[n,m] * Wh[h,b,m,o] ----------------
// grid 256 = (h*32+b)*2 + ochunk ; 128 threads, each owns 4 o.
__global__ __launch_bounds__(128) void k3_hprime(const float* __restrict__ Wh,
                                                 const float* __restrict__ att,
                                                 float* __restrict__ hp) {
  int blk = blockIdx.x;
  int hb = blk >> 1, oc = blk & 1;
  int t = threadIdx.x;
  __shared__ float att_s[196];
  for (int idx = t; idx < 196; idx += 128) att_s[idx] = att[hb * 196 + idx];
  __syncthreads();

  int o4 = oc * 512 + 4 * t;
  const float* whp = Wh + (size_t)hb * 14336;
  float4 acc[14];
  #pragma unroll
  for (int n = 0; n < 14; ++n) acc[n] = make_float4(0.f, 0.f, 0.f, 0.f);
  #pragma unroll
  for (int m = 0; m < 14; ++m) {
    float4 wm = *(const float4*)(whp + m * 1024 + o4);
    #pragma unroll
    for (int n = 0; n < 14; ++n) {
      float anm = att_s[n * 14 + m];   // wave-uniform -> broadcast
      acc[n].x += anm * wm.x;
      acc[n].y += anm * wm.y;
      acc[n].z += anm * wm.z;
      acc[n].w += anm * wm.w;
    }
  }
  float* dst = hp + (size_t)hb * 14336 + o4;
  #pragma unroll
  for (int n = 0; n < 14; ++n) *(float4*)(dst + n * 1024) = acc[n];
}

// ---------------- Kernel 4: fc via bf16 MFMA: out_acc[b,o] += sum_f hp[h,b,f]*fcw[h,o,f] ----------------
// grid 512 = kc(8) | oc(16) | h(4) ; 256 threads (4 waves). Block tile 32b x 64o, K_T=256.
// LDS rows padded to 272 bf16 (544 B) so frag reads land ~2-way on banks (free).
__global__ __launch_bounds__(256) void k4_fc(const float* __restrict__ hp,
                                             const float* __restrict__ fcw,
                                             float* __restrict__ oacc) {
  int blk = blockIdx.x;
  int kc = blk & 7;
  int oc = (blk >> 3) & 15;
  int h  = blk >> 7;
  int t = threadIdx.x;
  int lane = t & 63, w = t >> 6;
  int mw = w & 1, nw = w >> 1;
  __shared__ __align__(16) short As[32][272];
  __shared__ __align__(16) short Bs[64][272];
  const int o0 = oc * 64;
  const size_t hpb = (size_t)h * 32 * 14336;
  const size_t fwb = (size_t)h * 1024 * 14336;
  f32x4 c0 = {0.f, 0.f, 0.f, 0.f};
  f32x4 c1 = {0.f, 0.f, 0.f, 0.f};

  for (int tt = 0; tt < 7; ++tt) {
    int f0 = kc * 1792 + tt * 256;
    // stage A (32 x 256 fp32 -> bf16)
    #pragma unroll
    for (int p = 0; p < 8; ++p) {
      int f4 = p * 256 + t;
      int row = f4 >> 6, c4 = f4 & 63;
      float4 wv = *(const float4*)(hp + hpb + (size_t)row * 14336 + f0 + 4 * c4);
      short4 s4 = make_short4(f2b(wv.x), f2b(wv.y), f2b(wv.z), f2b(wv.w));
      *(short4*)&As[row][4 * c4] = s4;
    }
    // stage B (64 x 256 fp32 -> bf16); fcw is [o][f] i.e. already B^T (n-major, k-contiguous)
    #pragma unroll
    for (int p = 0; p < 16; ++p) {
      int f4 = p * 256 + t;
      int row = f4 >> 6, c4 = f4 & 63;
      float4 wv = *(const float4*)(fcw + fwb + (size_t)(o0 + row) * 14336 + f0 + 4 * c4);
      short4 s4 = make_short4(f2b(wv.x), f2b(wv.y), f2b(wv.z), f2b(wv.w));
      *(short4*)&Bs[row][4 * c4] = s4;
    }
    __syncthreads();
    #pragma unroll
    for (int ks = 0; ks < 8; ++ks) {
      bf16x8 af = *(const bf16x8*)&As[mw * 16 + (lane & 15)][ks * 32 + (lane >> 4) * 8];
      bf16x8 b0 = *(const bf16x8*)&Bs[nw * 32 + (lane & 15)][ks * 32 + (lane >> 4) * 8];
      bf16x8 b1 = *(const bf16x8*)&Bs[nw * 32 + 16 + (lane & 15)][ks * 32 + (lane >> 4) * 8];
      c0 = __builtin_amdgcn_mfma_f32_16x16x32_bf16(af, b0, c0, 0, 0, 0);
      c1 = __builtin_amdgcn_mfma_f32_16x16x32_bf16(af, b1, c1, 0, 0, 0);
    }
    __syncthreads();
  }
  // C/D layout: col = lane&15, row = (lane>>4)*4 + reg  [m89-verified]
  int br   = mw * 16 + (lane >> 4) * 4;
  int ocol = o0 + nw * 32 + (lane & 15);
  #pragma unroll
  for (int r = 0; r < 4; ++r) {
    atomicAdd(&oacc[(br + r) * 1024 + ocol],      c0[r]);
    atomicAdd(&oacc[(br + r) * 1024 + ocol + 16], c1[r]);
  }
}

// ---------------- Kernel 5: out[b,o] = log_softmax(out_acc[b,:] + sum_h fc_b[h,:]) ----------------
__global__ __launch_bounds__(256) void k5_lsm(const float* __restrict__ oacc,
                                              const float* __restrict__ fcb,
                                              float* __restrict__ out) {
  int b = blockIdx.x, t = threadIdx.x;
  int lane = t & 63, wid = t >> 6;
  __shared__ float redm[4], reds[4];
  float v[4];
  float mx = -1e30f;
  #pragma unroll
  for (int j = 0; j < 4; ++j) {
    int o = t + 256 * j;
    float val = oacc[b * 1024 + o] + fcb[o] + fcb[1024 + o] + fcb[2048 + o] + fcb[3072 + o];
    v[j] = val;
    mx = fmaxf(mx, val);
  }
  #pragma unroll
  for (int s = 32; s >= 1; s >>= 1) mx = fmaxf(mx, __shfl_xor(mx, s));
  if (lane == 0) redm[wid] = mx;
  __syncthreads();
  mx = fmaxf(fmaxf(redm[0], redm[1]), fmaxf(redm[2], redm[3]));
  float sm = 0.f;
  #pragma unroll
  for (int j = 0; j < 4; ++j) sm += expf(v[j] - mx);
  #pragma unroll
  for (int s = 32; s >= 1; s >>= 1) sm += __shfl_xor(sm, s);
  if (lane == 0) reds[wid] = sm;
  __syncthreads();
  sm = reds[0] + reds[1] + reds[2] + reds[3];
  float lse = mx + logf(sm);
  #pragma unroll
  for (int j = 0; j < 4; ++j) {
    int o = t + 256 * j;
    out[b * 1024 + o] = v[j] - lse;
  }
}

extern "C" void kernel_launch(void* const* d_in, const int* in_sizes, int n_in,
                              void* d_out, int out_size, void* d_ws, size_t ws_size,
                              hipStream_t stream) {
  const float* x   = (const float*)d_in[0];
  const float* adj = (const float*)d_in[1];
  const float* W   = (const float*)d_in[2];
  const float* a   = (const float*)d_in[3];
  const float* fcw = (const float*)d_in[4];
  const float* fcb = (const float*)d_in[5];
  float* out = (float*)d_out;

  char* ws = (char*)d_ws;
  float* Wh  = (float*)(ws);               // 4*32*14*1024*4   = 7,340,032 B
  float* att = (float*)(ws + 7340032);     // 4*32*196*4       =   100,352 B
  float* hp  = (float*)(ws + 7440384);     // 4*32*14*1024*4   = 7,340,032 B
  float* oac = (float*)(ws + 14780416);    // 32*1024*4        =   131,072 B

  hipMemsetAsync(Wh, 0, 7340032, stream);   // atomicAdd targets
  hipMemsetAsync(oac, 0, 131072, stream);

  k1_wh<<<512, 256, 0, stream>>>(x, W, Wh);
  k2_att<<<128, 64, 0, stream>>>(Wh, adj, a, att);
  k3_hprime<<<256, 128, 0, stream>>>(Wh, att, hp);
  k4_fc<<<512, 256, 0, stream>>>(hp, fcw, oac);
  k5_lsm<<<32, 256, 0, stream>>>(oac, fcb, out);
}

// Round 2
// 895.093 us; speedup vs baseline: 1.0757x; 1.0757x over previous
//
#include <hip/hip_runtime.h>
#include <hip/hip_bf16.h>

#define ALPHA 0.2f
#define NEGV  -9000000000000000.0f

typedef __attribute__((ext_vector_type(8))) short bf16x8;
typedef __attribute__((ext_vector_type(4))) float f32x4;

// fp32 -> bf16 (RNE) bit trick; inputs are finite so no NaN care needed.
__device__ __forceinline__ short f2b(float f) {
  unsigned u = __float_as_uint(f);
  unsigned r = (u + 0x7FFFu + ((u >> 16) & 1u)) >> 16;
  return (short)r;
}

// ---------------- Kernel 1: Whp[kc][h,b,n,o] = partial sum_i x[b,n,i] * W[h,b,i,o] ----------------
// grid 512 = (h*32+b)*4 + kchunk ; 256 threads; plain stores into per-kc partial buffers (no atomics).
__global__ __launch_bounds__(256) void k1_wh(const float* __restrict__ x,
                                             const float* __restrict__ W,
                                             float* __restrict__ Whp) {
  int blk = blockIdx.x;
  int kc = blk & 3;
  int hb = blk >> 2;          // h*32+b
  int b  = hb & 31;
  int t  = threadIdx.x;
  __shared__ float xs[14][256];
  int i0 = kc * 256;
  const float* xb = x + (size_t)b * 14 * 1024 + i0;
  #pragma unroll
  for (int n = 0; n < 14; ++n) xs[n][t] = xb[n * 1024 + t];
  __syncthreads();

  const float* Wp = W + ((size_t)hb * 1024 + i0) * 1024 + 4 * t;   // o = 4t..4t+3
  float4 acc[14];
  #pragma unroll
  for (int n = 0; n < 14; ++n) acc[n] = make_float4(0.f, 0.f, 0.f, 0.f);

  for (int ii = 0; ii < 256; ii += 4) {
    float4 w0 = *(const float4*)(Wp + (size_t)(ii + 0) * 1024);
    float4 w1 = *(const float4*)(Wp + (size_t)(ii + 1) * 1024);
    float4 w2 = *(const float4*)(Wp + (size_t)(ii + 2) * 1024);
    float4 w3 = *(const float4*)(Wp + (size_t)(ii + 3) * 1024);
    #pragma unroll
    for (int n = 0; n < 14; ++n) {
      float4 xn = *(const float4*)&xs[n][ii];   // wave-uniform -> LDS broadcast
      acc[n].x += xn.x * w0.x + xn.y * w1.x + xn.z * w2.x + xn.w * w3.x;
      acc[n].y += xn.x * w0.y + xn.y * w1.y + xn.z * w2.y + xn.w * w3.y;
      acc[n].z += xn.x * w0.z + xn.y * w1.z + xn.z * w2.z + xn.w * w3.z;
      acc[n].w += xn.x * w0.w + xn.y * w1.w + xn.z * w2.w + xn.w * w3.w;
    }
  }

  float* dst = Whp + (size_t)kc * 1835008 + (size_t)hb * 14336 + 4 * t;
  #pragma unroll
  for (int n = 0; n < 14; ++n) *(float4*)(dst + n * 1024) = acc[n];
}

// ---------------- Kernel 1b: Wh = Whp[0]+Whp[1]+Whp[2]+Whp[3] ----------------
// grid 1792 x 256, float4 per thread.
__global__ __launch_bounds__(256) void k1b_red(const float* __restrict__ p,
                                               float* __restrict__ Wh) {
  size_t idx = ((size_t)blockIdx.x * 256 + threadIdx.x) * 4;
  const size_t S = 1835008;
  float4 a = *(const float4*)(p + idx);
  float4 b = *(const float4*)(p + S + idx);
  float4 c = *(const float4*)(p + 2 * S + idx);
  float4 d = *(const float4*)(p + 3 * S + idx);
  a.x += b.x + c.x + d.x;
  a.y += b.y + c.y + d.y;
  a.z += b.z + c.z + d.z;
  a.w += b.w + c.w + d.w;
  *(float4*)(Wh + idx) = a;
}

// ---------------- Kernel 2: attention matrix (softmax over axis=2 == n, per column m) ----------------
// grid 128 = h*32+b ; 128 threads (2 waves, 7 n each).
__global__ __launch_bounds__(128) void k2_att(const float* __restrict__ Wh,
                                              const float* __restrict__ adj,
                                              const float* __restrict__ a,
                                              float* __restrict__ att) {
  int hb = blockIdx.x;
  int b  = hb & 31;
  int t  = threadIdx.x;
  int l  = t & 63, w = t >> 6;
  __shared__ float wh1s[14], wh2s[14];
  const float* whp = Wh + (size_t)hb * 14336;
  const float* a1  = a + (size_t)hb * 2048;
  const float* a2  = a1 + 1024;

  for (int nn = 0; nn < 7; ++nn) {
    int n = w * 7 + nn;
    float p1 = 0.f, p2 = 0.f;
    #pragma unroll
    for (int j = 0; j < 16; ++j) {
      int o = l + 64 * j;
      float wv = whp[n * 1024 + o];
      p1 += wv * a1[o];
      p2 += wv * a2[o];
    }
    #pragma unroll
    for (int s = 32; s >= 1; s >>= 1) {
      p1 += __shfl_xor(p1, s);
      p2 += __shfl_xor(p2, s);
    }
    if (l == 0) { wh1s[n] = p1; wh2s[n] = p2; }
  }
  __syncthreads();

  if (t < 14) {
    int m = t;
    const float* adjb = adj + b * 196;
    float col[14];
    float mx = -1e30f;
    #pragma unroll
    for (int n = 0; n < 14; ++n) {
      float e = wh1s[n] + wh2s[m];
      e = (e > 0.f) ? e : ALPHA * e;
      e = (adjb[n * 14 + m] > 0.f) ? e : NEGV;
      col[n] = e;
      mx = fmaxf(mx, e);
    }
    float s = 0.f;
    #pragma unroll
    for (int n = 0; n < 14; ++n) { col[n] = expf(col[n] - mx); s += col[n]; }
    float inv = 1.f / s;
    #pragma unroll
    for (int n = 0; n < 14; ++n) att[hb * 196 + n * 14 + m] = col[n] * inv;
  }
}

// ---------------- Kernel 3: h_prime[h,b,n,o] = sum_m att[n,m] * Wh[h,b,m,o] ----------------
// grid 256 = (h*32+b)*2 + ochunk ; 128 threads, each owns 4 o.
__global__ __launch_bounds__(128) void k3_hprime(const float* __restrict__ Wh,
                                                 const float* __restrict__ att,
                                                 float* __restrict__ hp) {
  int blk = blockIdx.x;
  int hb = blk >> 1, oc = blk & 1;
  int t = threadIdx.x;
  __shared__ float att_s[196];
  for (int idx = t; idx < 196; idx += 128) att_s[idx] = att[hb * 196 + idx];
  __syncthreads();

  int o4 = oc * 512 + 4 * t;
  const float* whp = Wh + (size_t)hb * 14336;
  float4 acc[14];
  #pragma unroll
  for (int n = 0; n < 14; ++n) acc[n] = make_float4(0.f, 0.f, 0.f, 0.f);
  #pragma unroll
  for (int m = 0; m < 14; ++m) {
    float4 wm = *(const float4*)(whp + m * 1024 + o4);
    #pragma unroll
    for (int n = 0; n < 14; ++n) {
      float anm = att_s[n * 14 + m];   // wave-uniform -> broadcast
      acc[n].x += anm * wm.x;
      acc[n].y += anm * wm.y;
      acc[n].z += anm * wm.z;
      acc[n].w += anm * wm.w;
    }
  }
  float* dst = hp + (size_t)hb * 14336 + o4;
  #pragma unroll
  for (int n = 0; n < 14; ++n) *(float4*)(dst + n * 1024) = acc[n];
}

// ---------------- Kernel 4: fc via bf16 MFMA into per-(kc,h) partial tiles (no atomics) ----------------
// grid 512 = kc(8) | oc(16) | h(4) ; 256 threads (4 waves). Block tile 32b x 64o, K_T=256.
// LDS rows padded to 272 bf16 (544 B) so frag reads land ~2-way on banks (free).
__global__ __launch_bounds__(256) void k4_fc(const float* __restrict__ hp,
                                             const float* __restrict__ fcw,
                                             float* __restrict__ oaccp) {
  int blk = blockIdx.x;
  int kc = blk & 7;
  int oc = (blk >> 3) & 15;
  int h  = blk >> 7;
  int t = threadIdx.x;
  int lane = t & 63, w = t >> 6;
  int mw = w & 1, nw = w >> 1;
  __shared__ __align__(16) short As[32][272];
  __shared__ __align__(16) short Bs[64][272];
  const int o0 = oc * 64;
  const size_t hpb = (size_t)h * 32 * 14336;
  const size_t fwb = (size_t)h * 1024 * 14336;
  f32x4 c0 = {0.f, 0.f, 0.f, 0.f};
  f32x4 c1 = {0.f, 0.f, 0.f, 0.f};

  for (int tt = 0; tt < 7; ++tt) {
    int f0 = kc * 1792 + tt * 256;
    // stage A (32 x 256 fp32 -> bf16)
    #pragma unroll
    for (int p = 0; p < 8; ++p) {
      int f4 = p * 256 + t;
      int row = f4 >> 6, c4 = f4 & 63;
      float4 wv = *(const float4*)(hp + hpb + (size_t)row * 14336 + f0 + 4 * c4);
      short4 s4 = make_short4(f2b(wv.x), f2b(wv.y), f2b(wv.z), f2b(wv.w));
      *(short4*)&As[row][4 * c4] = s4;
    }
    // stage B (64 x 256 fp32 -> bf16); fcw is [o][f] i.e. already B^T (n-major, k-contiguous)
    #pragma unroll
    for (int p = 0; p < 16; ++p) {
      int f4 = p * 256 + t;
      int row = f4 >> 6, c4 = f4 & 63;
      float4 wv = *(const float4*)(fcw + fwb + (size_t)(o0 + row) * 14336 + f0 + 4 * c4);
      short4 s4 = make_short4(f2b(wv.x), f2b(wv.y), f2b(wv.z), f2b(wv.w));
      *(short4*)&Bs[row][4 * c4] = s4;
    }
    __syncthreads();
    #pragma unroll
    for (int ks = 0; ks < 8; ++ks) {
      bf16x8 af = *(const bf16x8*)&As[mw * 16 + (lane & 15)][ks * 32 + (lane >> 4) * 8];
      bf16x8 b0 = *(const bf16x8*)&Bs[nw * 32 + (lane & 15)][ks * 32 + (lane >> 4) * 8];
      bf16x8 b1 = *(const bf16x8*)&Bs[nw * 32 + 16 + (lane & 15)][ks * 32 + (lane >> 4) * 8];
      c0 = __builtin_amdgcn_mfma_f32_16x16x32_bf16(af, b0, c0, 0, 0, 0);
      c1 = __builtin_amdgcn_mfma_f32_16x16x32_bf16(af, b1, c1, 0, 0, 0);
    }
    __syncthreads();
  }
  // C/D layout: col = lane&15, row = (lane>>4)*4 + reg  [m89-verified]
  float* op = oaccp + (size_t)(kc * 4 + h) * 32768;   // [kc,h][b=32][o=1024]
  int br   = mw * 16 + (lane >> 4) * 4;
  int ocol = o0 + nw * 32 + (lane & 15);
  #pragma unroll
  for (int r = 0; r < 4; ++r) {
    op[(br + r) * 1024 + ocol]      = c0[r];
    op[(br + r) * 1024 + ocol + 16] = c1[r];
  }
}

// ---------------- Kernel 5: out[b,o] = log_softmax(sum_p oaccp[p][b,:] + sum_h fc_b[h,:]) ----------------
__global__ __launch_bounds__(256) void k5_lsm(const float* __restrict__ oaccp,
                                              const float* __restrict__ fcb,
                                              float* __restrict__ out) {
  int b = blockIdx.x, t = threadIdx.x;
  int lane = t & 63, wid = t >> 6;
  __shared__ float redm[4], reds[4];
  float v[4];
  float mx = -1e30f;
  #pragma unroll
  for (int j = 0; j < 4; ++j) {
    int o = t + 256 * j;
    float val = fcb[o] + fcb[1024 + o] + fcb[2048 + o] + fcb[3072 + o];
    #pragma unroll
    for (int p = 0; p < 32; ++p) val += oaccp[(size_t)p * 32768 + b * 1024 + o];
    v[j] = val;
    mx = fmaxf(mx, val);
  }
  #pragma unroll
  for (int s = 32; s >= 1; s >>= 1) mx = fmaxf(mx, __shfl_xor(mx, s));
  if (lane == 0) redm[wid] = mx;
  __syncthreads();
  mx = fmaxf(fmaxf(redm[0], redm[1]), fmaxf(redm[2], redm[3]));
  float sm = 0.f;
  #pragma unroll
  for (int j = 0; j < 4; ++j) sm += expf(v[j] - mx);
  #pragma unroll
  for (int s = 32; s >= 1; s >>= 1) sm += __shfl_xor(sm, s);
  if (lane == 0) reds[wid] = sm;
  __syncthreads();
  sm = reds[0] + reds[1] + reds[2] + reds[3];
  float lse = mx + logf(sm);
  #pragma unroll
  for (int j = 0; j < 4; ++j) {
    int o = t + 256 * j;
    out[b * 1024 + o] = v[j] - lse;
  }
}

extern "C" void kernel_launch(void* const* d_in, const int* in_sizes, int n_in,
                              void* d_out, int out_size, void* d_ws, size_t ws_size,
                              hipStream_t stream) {
  const float* x   = (const float*)d_in[0];
  const float* adj = (const float*)d_in[1];
  const float* W   = (const float*)d_in[2];
  const float* a   = (const float*)d_in[3];
  const float* fcw = (const float*)d_in[4];
  const float* fcb = (const float*)d_in[5];
  float* out = (float*)d_out;

  char* ws = (char*)d_ws;
  float* Whp = (float*)(ws);                // 4 * 7,340,032 = 29,360,128 B
  float* Wh  = (float*)(ws + 29360128);     // 7,340,032 B
  float* att = (float*)(ws + 36700160);     //   100,352 B
  float* hp  = (float*)(ws + 36800512);     // 7,340,032 B
  float* oap = (float*)(ws + 44140544);     // 32 * 32 * 1024 * 4 = 4,194,304 B

  k1_wh<<<512, 256, 0, stream>>>(x, W, Whp);
  k1b_red<<<1792, 256, 0, stream>>>(Whp, Wh);
  k2_att<<<128, 128, 0, stream>>>(Wh, adj, a, att);
  k3_hprime<<<256, 128, 0, stream>>>(Wh, att, hp);
  k4_fc<<<512, 256, 0, stream>>>(hp, fcw, oap);
  k5_lsm<<<32, 256, 0, stream>>>(oap, fcb, out);
}